// Round 4
// baseline (99.473 us; speedup 1.0000x reference)
//
#include <hip/hip_runtime.h>
#include <hip/hip_cooperative_groups.h>

namespace cg = cooperative_groups;

#define ALPHA 0.2f
#define N_ROWS 8192
#define N_FEAT 256

// Fused single cooperative launch:
//   Phase 1: dual dot products s_src/s_dst (each block: 8 rows, 2 per wave).
//   grid.sync()
//   Phase 2: out[i][j] = leaky_relu(s_src[i] + s_dst[j]) streamed as float4
//            stores with s_dst register-cached (round-1 structure; regular
//            stores — nt stores measured -20% in round 3).
// 1024 blocks x 256 threads = 4 blocks/CU co-resident (of 8 possible at
// 256 thr); __launch_bounds__(256,4) caps VGPR at 128 so the cooperative
// co-residency check passes with margin.
__global__ void __launch_bounds__(256, 4) attn_fused(const float* __restrict__ X,
                                                     const float* __restrict__ av,
                                                     float* __restrict__ s,
                                                     float* __restrict__ out) {
    const int wave = threadIdx.x >> 6;
    const int lane = threadIdx.x & 63;
    const int t    = threadIdx.x;

    // ---- Phase 1: per-row dual dot product, one wave per row, 2 rows/wave.
    const float4* asrc = reinterpret_cast<const float4*>(av);
    const float4* adst = reinterpret_cast<const float4*>(av + N_FEAT);
    const float4  as   = asrc[lane];
    const float4  ad   = adst[lane];

    #pragma unroll
    for (int rr = 0; rr < 2; ++rr) {
        const int row = blockIdx.x * 8 + rr * 4 + wave;
        const float4 x =
            reinterpret_cast<const float4*>(X + (size_t)row * N_FEAT)[lane];
        float ds = x.x * as.x + x.y * as.y + x.z * as.z + x.w * as.w;
        float dd = x.x * ad.x + x.y * ad.y + x.z * ad.z + x.w * ad.w;
        #pragma unroll
        for (int off = 32; off > 0; off >>= 1) {
            ds += __shfl_down(ds, off, 64);
            dd += __shfl_down(dd, off, 64);
        }
        if (lane == 0) {
            s[row]          = ds;   // s_src
            s[N_ROWS + row] = dd;   // s_dst
        }
    }

    cg::this_grid().sync();

    // ---- Phase 2: block owns rows [8b, 8b+8) x all 8192 columns.
    const int     row0 = blockIdx.x * 8;
    const float4* sd4  = reinterpret_cast<const float4*>(s + N_ROWS);
    float4*       o4   = reinterpret_cast<float4*>(out);

    // Cache this thread's 8 column chunks of s_dst (32 KB/block from L2,
    // reused across 8 rows = 256 KB of output).
    float4 sd[8];
    #pragma unroll
    for (int c = 0; c < 8; ++c)
        sd[c] = sd4[c * 256 + t];

    #pragma unroll
    for (int r = 0; r < 8; ++r) {
        const float  ss   = s[row0 + r];                 // block-uniform
        const size_t base = (size_t)(row0 + r) * (N_ROWS / 4);
        #pragma unroll
        for (int c = 0; c < 8; ++c) {
            float4 v;
            float  u;
            u = ss + sd[c].x; v.x = fmaxf(u, ALPHA * u);
            u = ss + sd[c].y; v.y = fmaxf(u, ALPHA * u);
            u = ss + sd[c].z; v.z = fmaxf(u, ALPHA * u);
            u = ss + sd[c].w; v.w = fmaxf(u, ALPHA * u);
            o4[base + c * 256 + t] = v;
        }
    }
}

extern "C" void kernel_launch(void* const* d_in, const int* in_sizes, int n_in,
                              void* d_out, int out_size, void* d_ws, size_t ws_size,
                              hipStream_t stream) {
    const float* X  = (const float*)d_in[0];   // feature_matrix [8192, 256]
    const float* av = (const float*)d_in[1];   // attention_vector [512, 1]
    float* out = (float*)d_out;                // [8192, 8192]
    float* s   = (float*)d_ws;                 // [2 * 8192] scratch

    void* args[] = { (void*)&X, (void*)&av, (void*)&s, (void*)&out };
    hipLaunchCooperativeKernel(reinterpret_cast<void*>(attn_fused),
                               dim3(N_ROWS / 8), dim3(256), args, 0, stream);
}

// Round 5
// 48.414 us; speedup vs baseline: 2.0547x; 2.0547x over previous
//
#include <hip/hip_runtime.h>

#define ALPHA 0.2f
#define N_ROWS 8192
#define N_FEAT 256

// Kernel 1: per-row dual dot product. One wave (64 lanes) per row,
// each lane loads one float4 (16B) of the row -> 64*4 = 256 features.
__global__ void __launch_bounds__(256) attn_dots(const float* __restrict__ X,
                                                 const float* __restrict__ av,
                                                 float* __restrict__ s) {
    const int wave = threadIdx.x >> 6;
    const int lane = threadIdx.x & 63;
    const int row  = blockIdx.x * 4 + wave;

    const float4* xr   = reinterpret_cast<const float4*>(X + (size_t)row * N_FEAT);
    const float4* asrc = reinterpret_cast<const float4*>(av);
    const float4* adst = reinterpret_cast<const float4*>(av + N_FEAT);

    float4 x  = xr[lane];
    float4 as = asrc[lane];
    float4 ad = adst[lane];

    float ds = x.x * as.x + x.y * as.y + x.z * as.z + x.w * as.w;
    float dd = x.x * ad.x + x.y * ad.y + x.z * ad.z + x.w * ad.w;

    #pragma unroll
    for (int off = 32; off > 0; off >>= 1) {
        ds += __shfl_down(ds, off, 64);
        dd += __shfl_down(dd, off, 64);
    }
    if (lane == 0) {
        s[row]          = ds;   // s_src
        s[N_ROWS + row] = dd;   // s_dst
    }
}

// Kernel 2: out[i][j] = leaky_relu(s_src[i] + s_dst[j]).
// One float4 store per thread; blockIdx.y = row, blockIdx.x = column chunk.
// Measured best structure (48.48 us): regular cached stores (nt = -20%,
// round 3), thin blocks (fat register-caching blocks = neutral, round 1),
// two stream-ordered dispatches (coop fusion = -2x, round 4).
__global__ void __launch_bounds__(256) attn_bcast(const float* __restrict__ s,
                                                  float* __restrict__ out) {
    const int row = blockIdx.y;
    const int j4  = blockIdx.x * 256 + threadIdx.x;   // float4 column index [0, 2048)

    const float ssrc = s[row];
    const float4 sd  = reinterpret_cast<const float4*>(s + N_ROWS)[j4];

    float4 o;
    float v;
    v = ssrc + sd.x; o.x = (v >= 0.f) ? v : ALPHA * v;
    v = ssrc + sd.y; o.y = (v >= 0.f) ? v : ALPHA * v;
    v = ssrc + sd.z; o.z = (v >= 0.f) ? v : ALPHA * v;
    v = ssrc + sd.w; o.w = (v >= 0.f) ? v : ALPHA * v;

    reinterpret_cast<float4*>(out)[(size_t)row * (N_ROWS / 4) + j4] = o;
}

extern "C" void kernel_launch(void* const* d_in, const int* in_sizes, int n_in,
                              void* d_out, int out_size, void* d_ws, size_t ws_size,
                              hipStream_t stream) {
    const float* X  = (const float*)d_in[0];   // feature_matrix [8192, 256]
    const float* av = (const float*)d_in[1];   // attention_vector [512, 1]
    float* out = (float*)d_out;                // [8192, 8192]
    float* s   = (float*)d_ws;                 // [2 * 8192] scratch

    // Kernel 1: 8192 rows / 4 rows-per-block = 2048 blocks of 256 threads.
    attn_dots<<<dim3(N_ROWS / 4), dim3(256), 0, stream>>>(X, av, s);

    // Kernel 2: 8192 rows x (8192/4 float4s / 256 threads = 8) column chunks.
    attn_bcast<<<dim3(8, N_ROWS), dim3(256), 0, stream>>>(s, out);
}